// Round 1
// baseline (166.143 us; speedup 1.0000x reference)
//
#include <hip/hip_runtime.h>

#define TD_ 9
#define DIN_ 135

__device__ __forceinline__ float lrelu(float x) { return x >= 0.f ? x : 0.2f * x; }

// pack t = x[:, 126:135] into [N,9] contiguous (makes the E-edge gather L2-resident)
__global__ void k_pack_t(const float* __restrict__ x, float* __restrict__ t, int n) {
  int total = n * TD_;
  for (int i = blockIdx.x * blockDim.x + threadIdx.x; i < total; i += gridDim.x * blockDim.x) {
    int v = i / TD_, k = i - v * TD_;
    t[i] = x[(size_t)v * DIN_ + (DIN_ - TD_) + k];
  }
}

// cosine-sim accumulation over all E edges + mark S3 = {0} ∪ N_in(0)
__global__ void k_sim_mark3(const float* __restrict__ t, const int* __restrict__ src,
                            const int* __restrict__ dst, int E,
                            float* __restrict__ simsum, int* __restrict__ flag) {
  int gtid = blockIdx.x * blockDim.x + threadIdx.x;
  if (gtid == 0) flag[0] = 1;
  float local = 0.f;
  for (int e = gtid; e < E; e += gridDim.x * blockDim.x) {
    int s = src[e], d = dst[e];
    if (d == 0) flag[s] = 1;
    const float* ti = t + (size_t)s * TD_;
    const float* tj = t + (size_t)d * TD_;
    float dot = 0.f, na = 0.f, nb = 0.f;
#pragma unroll
    for (int k = 0; k < TD_; k++) { float a = ti[k], b = tj[k]; dot += a * b; na += a * a; nb += b * b; }
    local += dot / (fmaxf(sqrtf(na), 1e-8f) * fmaxf(sqrtf(nb), 1e-8f));
  }
  for (int off = 32; off > 0; off >>= 1) local += __shfl_down(local, off, 64);
  __shared__ float wsum[8];
  int lane = threadIdx.x & 63, wid = threadIdx.x >> 6;
  if (lane == 0) wsum[wid] = local;
  __syncthreads();
  if (threadIdx.x == 0) {
    float s = 0.f;
    int nw = blockDim.x >> 6;
    for (int w = 0; w < nw; w++) s += wsum[w];
    atomicAdd(simsum, s);
  }
}

// if dstMap[dst] >= 0, mark src
__global__ void k_mark(const int* __restrict__ src, const int* __restrict__ dst, int E,
                       const int* __restrict__ dstMap, int* __restrict__ flag) {
  for (int e = blockIdx.x * blockDim.x + threadIdx.x; e < E; e += gridDim.x * blockDim.x)
    if (dstMap[dst[e]] >= 0) flag[src[e]] = 1;
}

// compact flagged (or previously-mapped) nodes into list + position map
__global__ void k_compact(const int* __restrict__ flag, const int* __restrict__ prevMap,
                          int* __restrict__ map, int* __restrict__ list,
                          int* __restrict__ cnt, int n, int cap) {
  int v = blockIdx.x * blockDim.x + threadIdx.x;
  if (v >= n) return;
  bool in = (flag[v] != 0) || (prevMap && prevMap[v] >= 0);
  if (in) {
    int p = atomicAdd(cnt, 1);
    if (p < cap) { list[p] = v; map[v] = p; }
  }
}

// extract edge lists into S2 (for GAT1), S3 (for GAT2), {0} (for GAT3)
__global__ void k_extract(const int* __restrict__ src, const int* __restrict__ dst, int E,
                          const int* __restrict__ m1, const int* __restrict__ m2, const int* __restrict__ m3,
                          int* e1s, int* e1d, int* c1,
                          int* e2s, int* e2d, int* c2,
                          int* e3s, int* e3d, int* c3,
                          int cap1, int cap2, int cap3) {
  for (int e = blockIdx.x * blockDim.x + threadIdx.x; e < E; e += gridDim.x * blockDim.x) {
    int s = src[e], d = dst[e];
    if (m2[d] >= 0) { int p = atomicAdd(c1, 1); if (p < cap1) { e1s[p] = m1[s]; e1d[p] = d; } }
    if (m3[d] >= 0) { int p = atomicAdd(c2, 1); if (p < cap2) { e2s[p] = m2[s]; e2d[p] = d; } }
    if (d == 0)     { int p = atomicAdd(c3, 1); if (p < cap3) { e3s[p] = m3[s]; e3d[p] = 0; } }
  }
}

// h0[p] = x[list1[p]] @ W_in + b_in   (one block per node, 128 threads)
__global__ __launch_bounds__(128) void k_h0(const float* __restrict__ x, const float* __restrict__ W,
                                            const float* __restrict__ b,
                                            const int* __restrict__ list1, const int* __restrict__ cntp,
                                            int cap, float* __restrict__ h0) {
  __shared__ float xs[DIN_];
  int cnt = *cntp; if (cnt > cap) cnt = cap;
  for (int p = blockIdx.x; p < cnt; p += gridDim.x) {
    int v = list1[p];
    for (int k = threadIdx.x; k < DIN_; k += 128) xs[k] = x[(size_t)v * DIN_ + k];
    __syncthreads();
    int j = threadIdx.x;
    float acc = b[j];
    for (int k = 0; k < DIN_; k++) acc += xs[k] * W[(size_t)k * 128 + j];
    h0[(size_t)p * 128 + j] = acc;
    __syncthreads();
  }
}

// hh[p] = hin[p] @ W (128 x OUTD); es/ed per head (OUTD = 4*C)
template <int OUTD>
__global__ __launch_bounds__(256) void k_proj(const float* __restrict__ hin, const float* __restrict__ W,
                                              const float* __restrict__ av, const float* __restrict__ bv,
                                              const int* __restrict__ cntp, int cap,
                                              float* __restrict__ hh, float* __restrict__ es,
                                              float* __restrict__ ed) {
  __shared__ float hs[128];
  __shared__ float ps[OUTD];
  __shared__ float pd[OUTD];
  int cnt = *cntp; if (cnt > cap) cnt = cap;
  for (int p = blockIdx.x; p < cnt; p += gridDim.x) {
    for (int k = threadIdx.x; k < 128; k += 256) hs[k] = hin[(size_t)p * 128 + k];
    __syncthreads();
#pragma unroll
    for (int jj = 0; jj < OUTD / 256; jj++) {
      int j = jj * 256 + threadIdx.x;
      float acc = 0.f;
      for (int k = 0; k < 128; k++) acc += hs[k] * W[(size_t)k * OUTD + j];
      hh[(size_t)p * OUTD + j] = acc;
      ps[j] = acc * av[j];
      pd[j] = acc * bv[j];
    }
    __syncthreads();
    if (threadIdx.x < 8) {
      const int C = OUTD / 4;
      int a = threadIdx.x & 3;
      const float* pr = (threadIdx.x < 4) ? ps : pd;
      float s = 0.f;
      for (int cix = 0; cix < C; cix++) s += pr[a * C + cix];
      if (threadIdx.x < 4) es[(size_t)p * 4 + a] = s; else ed[(size_t)p * 4 + a] = s;
    }
    __syncthreads();
  }
}

// GAT layer for a compacted dst set: exact softmax attention incl. appended self-loop,
// head-mean + bias, (optional scale), relu + residual(hres @ rW + rb), LayerNorm.
// CLS additionally runs the final classifier from node 0 and writes d_out[0..1].
template <int C, bool SCALE, bool CLS>
__global__ __launch_bounds__(4 * C) void k_gat(
    const int* __restrict__ listD, const int* __restrict__ cntDp, int capD,
    const int* __restrict__ selfMap,
    const int* __restrict__ eSrc, const int* __restrict__ eDst, const int* __restrict__ cntEp, int capE,
    const float* __restrict__ hh, const float* __restrict__ es, const float* __restrict__ ed,
    const float* __restrict__ hres,
    const float* __restrict__ gb, const float* __restrict__ rW, const float* __restrict__ rb,
    const float* __restrict__ ng, const float* __restrict__ nbv,
    const float* __restrict__ simsum, const float* __restrict__ twp, int E,
    float* __restrict__ hout,
    const float* __restrict__ c1W, const float* __restrict__ c1b,
    const float* __restrict__ clg, const float* __restrict__ clb,
    const float* __restrict__ c2W, const float* __restrict__ c2b,
    float* __restrict__ dout) {
  const int NT = 4 * C;
  const int ECAP = 2048;
  __shared__ int eidx[ECAP];
  __shared__ int ecnt_s;
  __shared__ float eds_s[4];
  __shared__ float hs[128];
  __shared__ float sh[NT];
  __shared__ float z[64];
  __shared__ float mu_s, rstd_s;

  int cntD = CLS ? 1 : min(*cntDp, capD);
  int nE = min(*cntEp, capE);
  float scale = 1.f;
  if (SCALE) scale = 1.1f + 0.1f * (*twp) * (*simsum) / (float)E;

  int tid = threadIdx.x;
  int a = tid / C;

  for (int q = blockIdx.x; q < cntD; q += gridDim.x) {
    int v = CLS ? 0 : listD[q];
    int sp = selfMap[v];
    if (tid == 0) ecnt_s = 0;
    __syncthreads();
    if (tid < 4) eds_s[tid] = ed[(size_t)sp * 4 + tid];
    for (int k = tid; k < 128; k += NT) hs[k] = hres[(size_t)sp * 128 + k];
    for (int i = tid; i < nE; i += NT)
      if (eDst[i] == v) { int p = atomicAdd(&ecnt_s, 1); if (p < ECAP) eidx[p] = eSrc[i]; }
    __syncthreads();
    int ne = min(ecnt_s, ECAP);
    float edv = eds_s[a];
    float eself = lrelu(es[(size_t)sp * 4 + a] + edv);
    float m = eself;
    for (int j = 0; j < ne; j++) m = fmaxf(m, lrelu(es[(size_t)eidx[j] * 4 + a] + edv));
    float den = expf(eself - m);
    for (int j = 0; j < ne; j++) den += expf(lrelu(es[(size_t)eidx[j] * 4 + a] + edv) - m);
    float rden = 1.f / (den + 1e-16f);
    float acc = expf(eself - m) * rden * hh[(size_t)sp * NT + tid];
    for (int j = 0; j < ne; j++) {
      int spj = eidx[j];
      float w = expf(lrelu(es[(size_t)spj * 4 + a] + edv) - m) * rden;
      acc += w * hh[(size_t)spj * NT + tid];
    }
    sh[tid] = acc;
    __syncthreads();
    float val = 0.f;
    if (tid < C) {
      float g = (sh[tid] + sh[C + tid] + sh[2 * C + tid] + sh[3 * C + tid]) * 0.25f + gb[tid];
      g *= scale;
      g = fmaxf(g, 0.f);
      float r = rb[tid];
      for (int k = 0; k < 128; k++) r += hs[k] * rW[(size_t)k * C + tid];
      val = g + r;
    }
    __syncthreads();
    if (tid < C) sh[tid] = val;
    __syncthreads();
    if (tid == 0) {
      float s = 0.f, s2 = 0.f;
      for (int k = 0; k < C; k++) { float u = sh[k]; s += u; s2 += u * u; }
      float mu = s / (float)C;
      mu_s = mu;
      rstd_s = rsqrtf(fmaxf(s2 / (float)C - mu * mu, 0.f) + 1e-5f);
    }
    __syncthreads();
    if (tid < C) {
      float o = (val - mu_s) * rstd_s * ng[tid] + nbv[tid];
      hout[(size_t)q * C + tid] = o;
      sh[tid] = o;
    }
    __syncthreads();
    if (CLS) {
      if (tid < 64) {
        float az = c1b[tid];
        for (int k = 0; k < 64; k++) az += sh[k] * c1W[k * 64 + tid];
        z[tid] = fmaxf(az, 0.f);
      }
      __syncthreads();
      if (tid == 0) {
        float s = 0.f, s2 = 0.f;
        for (int k = 0; k < 64; k++) { float u = z[k]; s += u; s2 += u * u; }
        float mu = s / 64.f;
        float rstd = rsqrtf(fmaxf(s2 / 64.f - mu * mu, 0.f) + 1e-5f);
        float o0 = c2b[0], o1 = c2b[1];
        for (int k = 0; k < 64; k++) {
          float zn = (z[k] - mu) * rstd * clg[k] + clb[k];
          o0 += zn * c2W[k * 2 + 0];
          o1 += zn * c2W[k * 2 + 1];
        }
        dout[0] = o0; dout[1] = o1;
      }
    }
    __syncthreads();
  }
}

extern "C" void kernel_launch(void* const* d_in, const int* in_sizes, int n_in,
                              void* d_out, int out_size, void* d_ws, size_t ws_size,
                              hipStream_t stream) {
  const float* x = (const float*)d_in[0];
  const int* ei = (const int*)d_in[1];
  int N = in_sizes[0] / DIN_;
  int E = in_sizes[1] / 2;
  const int* src0 = ei;
  const int* dst0 = ei + E;
  const float* W_in = (const float*)d_in[3]; const float* b_in = (const float*)d_in[4];
  const float* g1W = (const float*)d_in[5], *g1as = (const float*)d_in[6], *g1ad = (const float*)d_in[7], *g1b = (const float*)d_in[8];
  const float* g2W = (const float*)d_in[9], *g2as = (const float*)d_in[10], *g2ad = (const float*)d_in[11], *g2b = (const float*)d_in[12];
  const float* g3W = (const float*)d_in[13], *g3as = (const float*)d_in[14], *g3ad = (const float*)d_in[15], *g3b = (const float*)d_in[16];
  const float* r1W = (const float*)d_in[17], *r1b = (const float*)d_in[18];
  const float* r2W = (const float*)d_in[19], *r2b = (const float*)d_in[20];
  const float* r3W = (const float*)d_in[21], *r3b = (const float*)d_in[22];
  const float* n1g = (const float*)d_in[23], *n1b = (const float*)d_in[24];
  const float* n2g = (const float*)d_in[25], *n2b = (const float*)d_in[26];
  const float* n3g = (const float*)d_in[27], *n3b = (const float*)d_in[28];
  const float* tw  = (const float*)d_in[29];
  const float* c1W = (const float*)d_in[30], *c1b = (const float*)d_in[31];
  const float* clg = (const float*)d_in[32], *clb = (const float*)d_in[33];
  const float* c2W = (const float*)d_in[34], *c2b = (const float*)d_in[35];
  float* dout = (float*)d_out;

  const int CAP3 = 512, CAP2 = 2048;
  const int CAPE1 = 65536, CAPE2 = 16384, CAPE3 = 4096;

  char* B = (char*)d_ws;
  size_t off = 0;
  auto take = [&](size_t nbytes) -> size_t {
    size_t r = off;
    off += (nbytes + 255) & ~(size_t)255;
    return r;
  };
  size_t o_f   = take((size_t)N * 4 + 256);           // f[N] + 64 int counters
  size_t o_map = take((size_t)3 * N * 4);             // m3, m2, m1
  size_t o_l3  = take((size_t)CAP3 * 4);
  size_t o_l2  = take((size_t)CAP2 * 4);
  size_t o_tp  = take((size_t)N * TD_ * 4);
  size_t o_e1s = take((size_t)CAPE1 * 4);
  size_t o_e1d = take((size_t)CAPE1 * 4);
  size_t o_e2s = take((size_t)CAPE2 * 4);
  size_t o_e2d = take((size_t)CAPE2 * 4);
  size_t o_e3s = take((size_t)CAPE3 * 4);
  size_t o_e3d = take((size_t)CAPE3 * 4);
  size_t o_h1  = take((size_t)CAP2 * 128 * 4);
  size_t o_hh2 = take((size_t)CAP2 * 512 * 4);
  size_t o_es2 = take((size_t)CAP2 * 16);
  size_t o_ed2 = take((size_t)CAP2 * 16);
  size_t o_h2  = take((size_t)CAP3 * 128 * 4);
  size_t o_hh3 = take((size_t)CAP3 * 256 * 4);
  size_t o_es3 = take((size_t)CAP3 * 16);
  size_t o_ed3 = take((size_t)CAP3 * 16);
  size_t o_h3  = take(64 * 4);
  int CAP1 = 8192;
  while (CAP1 > 512) {
    size_t need = off + ((size_t)CAP1 * 4 + 256) + ((size_t)CAP1 * 512 + 256) +
                  ((size_t)CAP1 * 2048 + 256) + 2 * ((size_t)CAP1 * 16 + 256);
    if (need <= ws_size) break;
    CAP1 >>= 1;
  }
  size_t o_l1  = take((size_t)CAP1 * 4);
  size_t o_h0  = take((size_t)CAP1 * 128 * 4);
  size_t o_hh1 = take((size_t)CAP1 * 512 * 4);
  size_t o_es1 = take((size_t)CAP1 * 16);
  size_t o_ed1 = take((size_t)CAP1 * 16);

  int* f     = (int*)(B + o_f);
  int* cnts  = f + N;               // [0]=cnt3 [1]=cnt2 [2]=cnt1 [3]=cE1 [4]=cE2 [5]=cE3, [8]=simsum(float)
  int* m3    = (int*)(B + o_map);
  int* m2    = m3 + N;
  int* m1    = m2 + N;
  int* list3 = (int*)(B + o_l3);
  int* list2 = (int*)(B + o_l2);
  int* list1 = (int*)(B + o_l1);
  float* tp  = (float*)(B + o_tp);
  int* e1s = (int*)(B + o_e1s); int* e1d = (int*)(B + o_e1d);
  int* e2s = (int*)(B + o_e2s); int* e2d = (int*)(B + o_e2d);
  int* e3s = (int*)(B + o_e3s); int* e3d = (int*)(B + o_e3d);
  float* h0  = (float*)(B + o_h0);
  float* hh1 = (float*)(B + o_hh1);
  float* es1 = (float*)(B + o_es1); float* ed1 = (float*)(B + o_ed1);
  float* h1  = (float*)(B + o_h1);
  float* hh2 = (float*)(B + o_hh2);
  float* es2 = (float*)(B + o_es2); float* ed2 = (float*)(B + o_ed2);
  float* h2  = (float*)(B + o_h2);
  float* hh3 = (float*)(B + o_hh3);
  float* es3 = (float*)(B + o_es3); float* ed3 = (float*)(B + o_ed3);
  float* h3  = (float*)(B + o_h3);
  float* simsum = (float*)&cnts[8];

  hipMemsetAsync(f, 0, (size_t)N * 4 + 256, stream);
  hipMemsetAsync(m3, 0xFF, (size_t)3 * N * 4, stream);

  int nbN = (N + 255) / 256;
  k_pack_t<<<512, 256, 0, stream>>>(x, tp, N);
  k_sim_mark3<<<1024, 256, 0, stream>>>(tp, src0, dst0, E, simsum, f);
  k_compact<<<nbN, 256, 0, stream>>>(f, (const int*)nullptr, m3, list3, &cnts[0], N, CAP3);
  k_mark<<<1024, 256, 0, stream>>>(src0, dst0, E, m3, f);
  k_compact<<<nbN, 256, 0, stream>>>(f, m3, m2, list2, &cnts[1], N, CAP2);
  k_mark<<<1024, 256, 0, stream>>>(src0, dst0, E, m2, f);
  k_compact<<<nbN, 256, 0, stream>>>(f, m2, m1, list1, &cnts[2], N, CAP1);
  k_extract<<<1024, 256, 0, stream>>>(src0, dst0, E, m1, m2, m3,
                                      e1s, e1d, &cnts[3], e2s, e2d, &cnts[4], e3s, e3d, &cnts[5],
                                      CAPE1, CAPE2, CAPE3);
  k_h0<<<2048, 128, 0, stream>>>(x, W_in, b_in, list1, &cnts[2], CAP1, h0);
  k_proj<512><<<2048, 256, 0, stream>>>(h0, g1W, g1as, g1ad, &cnts[2], CAP1, hh1, es1, ed1);
  k_gat<128, true, false><<<256, 512, 0, stream>>>(
      list2, &cnts[1], CAP2, m1, e1s, e1d, &cnts[3], CAPE1,
      hh1, es1, ed1, h0, g1b, r1W, r1b, n1g, n1b, simsum, tw, E, h1,
      nullptr, nullptr, nullptr, nullptr, nullptr, nullptr, nullptr);
  k_proj<512><<<256, 256, 0, stream>>>(h1, g2W, g2as, g2ad, &cnts[1], CAP2, hh2, es2, ed2);
  k_gat<128, true, false><<<64, 512, 0, stream>>>(
      list3, &cnts[0], CAP3, m2, e2s, e2d, &cnts[4], CAPE2,
      hh2, es2, ed2, h1, g2b, r2W, r2b, n2g, n2b, simsum, tw, E, h2,
      nullptr, nullptr, nullptr, nullptr, nullptr, nullptr, nullptr);
  k_proj<256><<<64, 256, 0, stream>>>(h2, g3W, g3as, g3ad, &cnts[0], CAP3, hh3, es3, ed3);
  k_gat<64, false, true><<<1, 256, 0, stream>>>(
      list3, &cnts[0], CAP3, m3, e3s, e3d, &cnts[5], CAPE3,
      hh3, es3, ed3, h2, g3b, r3W, r3b, n3g, n3b, simsum, tw, E, h3,
      c1W, c1b, clg, clb, c2W, c2b, dout);
}

// Round 2
// 149.287 us; speedup vs baseline: 1.1129x; 1.1129x over previous
//
#include <hip/hip_runtime.h>

#define TD_ 9
#define DIN_ 135

__device__ __forceinline__ float lrelu(float x) { return x >= 0.f ? x : 0.2f * x; }

// CAS-claim node v into (m, list, cnt). m[v] must start at -1.
__device__ __forceinline__ void claim_node(int v, int* __restrict__ m, int* __restrict__ list,
                                           int* __restrict__ cnt, int cap) {
  if (atomicCAS(&m[v], -1, -2) == -1) {
    int p = atomicAdd(cnt, 1);
    if (p < cap) { list[p] = v; m[v] = p; } else { m[v] = -3; }
  }
}

// init maps to -1, counters to 0, and pack t = x[:, 126:135] into [N,9]
__global__ void k_init_pack(const float* __restrict__ x, float* __restrict__ tp,
                            int* __restrict__ maps, int* __restrict__ cnts, int N) {
  int stride = gridDim.x * blockDim.x;
  int gtid = blockIdx.x * blockDim.x + threadIdx.x;
  int n3 = 3 * N;
  int nv = n3 >> 2;
  int4* mv = (int4*)maps;
  int4 neg = make_int4(-1, -1, -1, -1);
  for (int i = gtid; i < nv; i += stride) mv[i] = neg;
  for (int i = (nv << 2) + gtid; i < n3; i += stride) maps[i] = -1;
  if (gtid < 64) cnts[gtid] = 0;
  int total = N * TD_;
  for (int i = gtid; i < total; i += stride) {
    int v = i / TD_, k = i - v * TD_;
    tp[i] = x[(size_t)v * DIN_ + (DIN_ - TD_) + k];
  }
}

// cosine-sim accumulation over all E edges + claim S3 = {0} ∪ N_in(0)
__global__ void k_sim_mark3(const float* __restrict__ t, const int* __restrict__ src,
                            const int* __restrict__ dst, int E,
                            float* __restrict__ simsum,
                            int* __restrict__ m3, int* __restrict__ list3, int* __restrict__ cnt3,
                            int cap3) {
  int gtid = blockIdx.x * blockDim.x + threadIdx.x;
  if (gtid == 0) claim_node(0, m3, list3, cnt3, cap3);
  float local = 0.f;
  for (int e = gtid; e < E; e += gridDim.x * blockDim.x) {
    int s = src[e], d = dst[e];
    if (d == 0) claim_node(s, m3, list3, cnt3, cap3);
    const float* ti = t + (size_t)s * TD_;
    const float* tj = t + (size_t)d * TD_;
    float dot = 0.f, na = 0.f, nb = 0.f;
#pragma unroll
    for (int k = 0; k < TD_; k++) { float a = ti[k], b = tj[k]; dot += a * b; na += a * a; nb += b * b; }
    local += dot / (fmaxf(sqrtf(na), 1e-8f) * fmaxf(sqrtf(nb), 1e-8f));
  }
  for (int off = 32; off > 0; off >>= 1) local += __shfl_down(local, off, 64);
  __shared__ float wsum[8];
  int lane = threadIdx.x & 63, wid = threadIdx.x >> 6;
  if (lane == 0) wsum[wid] = local;
  __syncthreads();
  if (threadIdx.x == 0) {
    float s = 0.f;
    int nw = blockDim.x >> 6;
    for (int w = 0; w < nw; w++) s += wsum[w];
    atomicAdd(simsum, s);
  }
}

// claim all of prev set into (m,list,cnt), then claim src of every edge whose dst is in prev set
__global__ void k_mark_claim(const int* __restrict__ src, const int* __restrict__ dst, int E,
                             const int* __restrict__ mPrev, const int* __restrict__ listPrev,
                             const int* __restrict__ cntPrevP, int capPrev,
                             int* __restrict__ m, int* __restrict__ list, int* __restrict__ cnt,
                             int cap) {
  int gtid = blockIdx.x * blockDim.x + threadIdx.x;
  int stride = gridDim.x * blockDim.x;
  int np = min(*cntPrevP, capPrev);
  for (int i = gtid; i < np; i += stride) claim_node(listPrev[i], m, list, cnt, cap);
  for (int e = gtid; e < E; e += stride)
    if (mPrev[dst[e]] >= 0) claim_node(src[e], m, list, cnt, cap);
}

// extract edge lists: e1 (dst in S2), e2 (dst in S3), e3 (dst == 0)
__global__ void k_extract(const int* __restrict__ src, const int* __restrict__ dst, int E,
                          const int* __restrict__ m1, const int* __restrict__ m2, const int* __restrict__ m3,
                          int* e1s, int* e1d, int* c1,
                          int* e2s, int* e2d, int* c2,
                          int* e3s, int* e3d, int* c3,
                          int cap1, int cap2, int cap3) {
  for (int e = blockIdx.x * blockDim.x + threadIdx.x; e < E; e += gridDim.x * blockDim.x) {
    int s = src[e], d = dst[e];
    if (m2[d] >= 0) { int p = atomicAdd(c1, 1); if (p < cap1) { e1s[p] = m1[s]; e1d[p] = d; } }
    if (m3[d] >= 0) { int p = atomicAdd(c2, 1); if (p < cap2) { e2s[p] = m2[s]; e2d[p] = d; } }
    if (d == 0)     { int p = atomicAdd(c3, 1); if (p < cap3) { e3s[p] = m3[s]; e3d[p] = 0; } }
  }
}

// per S1 node: h0 = x@W_in + b_in; hh1 = h0@g1W; es1/ed1 head sums
__global__ __launch_bounds__(256) void k_h0proj1(
    const float* __restrict__ x, const float* __restrict__ W_in, const float* __restrict__ b_in,
    const float* __restrict__ g1W, const float* __restrict__ g1as, const float* __restrict__ g1ad,
    const int* __restrict__ list1, const int* __restrict__ cntp, int cap,
    float* __restrict__ h0, float* __restrict__ hh1,
    float* __restrict__ es1, float* __restrict__ ed1) {
  __shared__ float xs[DIN_];
  __shared__ float hs[128];
  __shared__ float ps[512], pd[512];
  int cnt = min(*cntp, cap);
  for (int p = blockIdx.x; p < cnt; p += gridDim.x) {
    int v = list1[p];
    for (int k = threadIdx.x; k < DIN_; k += 256) xs[k] = x[(size_t)v * DIN_ + k];
    __syncthreads();
    if (threadIdx.x < 128) {
      int j = threadIdx.x;
      float acc = b_in[j];
      for (int k = 0; k < DIN_; k++) acc += xs[k] * W_in[(size_t)k * 128 + j];
      h0[(size_t)p * 128 + j] = acc;
      hs[j] = acc;
    }
    __syncthreads();
#pragma unroll
    for (int jj = 0; jj < 2; jj++) {
      int j = jj * 256 + threadIdx.x;
      float acc = 0.f;
      for (int k = 0; k < 128; k++) acc += hs[k] * g1W[(size_t)k * 512 + j];
      hh1[(size_t)p * 512 + j] = acc;
      ps[j] = acc * g1as[j];
      pd[j] = acc * g1ad[j];
    }
    __syncthreads();
    if (threadIdx.x < 8) {
      int a = threadIdx.x & 3;
      const float* pr = (threadIdx.x < 4) ? ps : pd;
      float s = 0.f;
      for (int c = 0; c < 128; c++) s += pr[a * 128 + c];
      if (threadIdx.x < 4) es1[(size_t)p * 4 + a] = s; else ed1[(size_t)p * 4 + a] = s;
    }
    __syncthreads();
  }
}

// GAT layer over compacted dst set. Fused epilogue: projection for the NEXT layer
// (ONEXT>0) or the final classifier (CLS).
template <int C, int ONEXT, bool SCALE, bool CLS>
__global__ __launch_bounds__(4 * C) void k_gat(
    const int* __restrict__ listD, const int* __restrict__ cntDp, int capD,
    const int* __restrict__ selfMap,
    const int* __restrict__ eSrc, const int* __restrict__ eDst, const int* __restrict__ cntEp, int capE,
    const float* __restrict__ hh, const float* __restrict__ es, const float* __restrict__ ed,
    const float* __restrict__ hres,
    const float* __restrict__ gb, const float* __restrict__ rW, const float* __restrict__ rb,
    const float* __restrict__ ng, const float* __restrict__ nbv,
    const float* __restrict__ simsum, const float* __restrict__ twp, int E,
    float* __restrict__ hout,
    const float* __restrict__ Wn, const float* __restrict__ avn, const float* __restrict__ bvn,
    float* __restrict__ hhn, float* __restrict__ esn, float* __restrict__ edn,
    const float* __restrict__ c1W, const float* __restrict__ c1b,
    const float* __restrict__ clg, const float* __restrict__ clb,
    const float* __restrict__ c2W, const float* __restrict__ c2b,
    float* __restrict__ dout) {
  const int NT = 4 * C;
  const int ECAP = 2048;
  const int PSZ = (ONEXT > 0) ? ONEXT : 1;
  __shared__ int eidx[ECAP];
  __shared__ int ecnt_s;
  __shared__ float eds_s[4];
  __shared__ float hs[128];
  __shared__ float sh[NT];
  __shared__ float psn_s[PSZ], pdn_s[PSZ];
  __shared__ float z[64];
  __shared__ float mu_s, rstd_s;

  int cntD = CLS ? 1 : min(*cntDp, capD);
  int nE = min(*cntEp, capE);
  float scale = 1.f;
  if (SCALE) scale = 1.1f + 0.1f * (*twp) * (*simsum) / (float)E;

  int tid = threadIdx.x;
  int a = tid / C;

  for (int q = blockIdx.x; q < cntD; q += gridDim.x) {
    int v = CLS ? 0 : listD[q];
    int sp = selfMap[v];
    if (tid == 0) ecnt_s = 0;
    __syncthreads();
    if (tid < 4) eds_s[tid] = ed[(size_t)sp * 4 + tid];
    for (int k = tid; k < 128; k += NT) hs[k] = hres[(size_t)sp * 128 + k];
    for (int i = tid; i < nE; i += NT)
      if (eDst[i] == v) { int p = atomicAdd(&ecnt_s, 1); if (p < ECAP) eidx[p] = eSrc[i]; }
    __syncthreads();
    int ne = min(ecnt_s, ECAP);
    float edv = eds_s[a];
    float eself = lrelu(es[(size_t)sp * 4 + a] + edv);
    float m = eself;
    for (int j = 0; j < ne; j++) m = fmaxf(m, lrelu(es[(size_t)eidx[j] * 4 + a] + edv));
    float den = expf(eself - m);
    for (int j = 0; j < ne; j++) den += expf(lrelu(es[(size_t)eidx[j] * 4 + a] + edv) - m);
    float rden = 1.f / (den + 1e-16f);
    float acc = expf(eself - m) * rden * hh[(size_t)sp * NT + tid];
    for (int j = 0; j < ne; j++) {
      int spj = eidx[j];
      float w = expf(lrelu(es[(size_t)spj * 4 + a] + edv) - m) * rden;
      acc += w * hh[(size_t)spj * NT + tid];
    }
    sh[tid] = acc;
    __syncthreads();
    float val = 0.f;
    if (tid < C) {
      float g = (sh[tid] + sh[C + tid] + sh[2 * C + tid] + sh[3 * C + tid]) * 0.25f + gb[tid];
      g *= scale;
      g = fmaxf(g, 0.f);
      float r = rb[tid];
      for (int k = 0; k < 128; k++) r += hs[k] * rW[(size_t)k * C + tid];
      val = g + r;
    }
    __syncthreads();
    if (tid < C) sh[tid] = val;
    __syncthreads();
    if (tid == 0) {
      float s = 0.f, s2 = 0.f;
      for (int k = 0; k < C; k++) { float u = sh[k]; s += u; s2 += u * u; }
      float mu = s / (float)C;
      mu_s = mu;
      rstd_s = rsqrtf(fmaxf(s2 / (float)C - mu * mu, 0.f) + 1e-5f);
    }
    __syncthreads();
    if (tid < C) {
      float o = (val - mu_s) * rstd_s * ng[tid] + nbv[tid];
      hout[(size_t)q * C + tid] = o;
      sh[tid] = o;
    }
    __syncthreads();
    if (ONEXT > 0) {
      for (int j = tid; j < ONEXT; j += NT) {
        float acc2 = 0.f;
        for (int k = 0; k < C; k++) acc2 += sh[k] * Wn[(size_t)k * ONEXT + j];
        hhn[(size_t)q * ONEXT + j] = acc2;
        psn_s[j] = acc2 * avn[j];
        pdn_s[j] = acc2 * bvn[j];
      }
      __syncthreads();
      if (tid < 8) {
        const int CN = ONEXT / 4;
        int an = tid & 3;
        const float* pr = (tid < 4) ? psn_s : pdn_s;
        float s = 0.f;
        for (int c = 0; c < CN; c++) s += pr[an * CN + c];
        if (tid < 4) esn[(size_t)q * 4 + an] = s; else edn[(size_t)q * 4 + an] = s;
      }
    }
    if (CLS) {
      if (tid < 64) {
        float az = c1b[tid];
        for (int k = 0; k < 64; k++) az += sh[k] * c1W[k * 64 + tid];
        z[tid] = fmaxf(az, 0.f);
      }
      __syncthreads();
      if (tid == 0) {
        float s = 0.f, s2 = 0.f;
        for (int k = 0; k < 64; k++) { float u = z[k]; s += u; s2 += u * u; }
        float mu = s / 64.f;
        float rstd = rsqrtf(fmaxf(s2 / 64.f - mu * mu, 0.f) + 1e-5f);
        float o0 = c2b[0], o1 = c2b[1];
        for (int k = 0; k < 64; k++) {
          float zn = (z[k] - mu) * rstd * clg[k] + clb[k];
          o0 += zn * c2W[k * 2 + 0];
          o1 += zn * c2W[k * 2 + 1];
        }
        dout[0] = o0; dout[1] = o1;
      }
    }
    __syncthreads();
  }
}

extern "C" void kernel_launch(void* const* d_in, const int* in_sizes, int n_in,
                              void* d_out, int out_size, void* d_ws, size_t ws_size,
                              hipStream_t stream) {
  const float* x = (const float*)d_in[0];
  const int* ei = (const int*)d_in[1];
  int N = in_sizes[0] / DIN_;
  int E = in_sizes[1] / 2;
  const int* src0 = ei;
  const int* dst0 = ei + E;
  const float* W_in = (const float*)d_in[3]; const float* b_in = (const float*)d_in[4];
  const float* g1W = (const float*)d_in[5], *g1as = (const float*)d_in[6], *g1ad = (const float*)d_in[7], *g1b = (const float*)d_in[8];
  const float* g2W = (const float*)d_in[9], *g2as = (const float*)d_in[10], *g2ad = (const float*)d_in[11], *g2b = (const float*)d_in[12];
  const float* g3W = (const float*)d_in[13], *g3as = (const float*)d_in[14], *g3ad = (const float*)d_in[15], *g3b = (const float*)d_in[16];
  const float* r1W = (const float*)d_in[17], *r1b = (const float*)d_in[18];
  const float* r2W = (const float*)d_in[19], *r2b = (const float*)d_in[20];
  const float* r3W = (const float*)d_in[21], *r3b = (const float*)d_in[22];
  const float* n1g = (const float*)d_in[23], *n1b = (const float*)d_in[24];
  const float* n2g = (const float*)d_in[25], *n2b = (const float*)d_in[26];
  const float* n3g = (const float*)d_in[27], *n3b = (const float*)d_in[28];
  const float* tw  = (const float*)d_in[29];
  const float* c1W = (const float*)d_in[30], *c1b = (const float*)d_in[31];
  const float* clg = (const float*)d_in[32], *clb = (const float*)d_in[33];
  const float* c2W = (const float*)d_in[34], *c2b = (const float*)d_in[35];
  float* dout = (float*)d_out;

  const int CAP3 = 512, CAP2 = 2048;
  const int CAPE1 = 65536, CAPE2 = 16384, CAPE3 = 4096;

  char* B = (char*)d_ws;
  size_t off = 0;
  auto take = [&](size_t nbytes) -> size_t {
    size_t r = off;
    off += (nbytes + 255) & ~(size_t)255;
    return r;
  };
  size_t o_cnt = take(256);                           // 64 int counters (+simsum at [8])
  size_t o_map = take((size_t)3 * N * 4);             // m3, m2, m1
  size_t o_l3  = take((size_t)CAP3 * 4);
  size_t o_l2  = take((size_t)CAP2 * 4);
  size_t o_tp  = take((size_t)N * TD_ * 4);
  size_t o_e1s = take((size_t)CAPE1 * 4);
  size_t o_e1d = take((size_t)CAPE1 * 4);
  size_t o_e2s = take((size_t)CAPE2 * 4);
  size_t o_e2d = take((size_t)CAPE2 * 4);
  size_t o_e3s = take((size_t)CAPE3 * 4);
  size_t o_e3d = take((size_t)CAPE3 * 4);
  size_t o_h1  = take((size_t)CAP2 * 128 * 4);
  size_t o_hh2 = take((size_t)CAP2 * 512 * 4);
  size_t o_es2 = take((size_t)CAP2 * 16);
  size_t o_ed2 = take((size_t)CAP2 * 16);
  size_t o_h2  = take((size_t)CAP3 * 128 * 4);
  size_t o_hh3 = take((size_t)CAP3 * 256 * 4);
  size_t o_es3 = take((size_t)CAP3 * 16);
  size_t o_ed3 = take((size_t)CAP3 * 16);
  size_t o_h3  = take(64 * 4);
  int CAP1 = 8192;
  while (CAP1 > 512) {
    size_t need = off + ((size_t)CAP1 * 4 + 256) + ((size_t)CAP1 * 512 + 256) +
                  ((size_t)CAP1 * 2048 + 256) + 2 * ((size_t)CAP1 * 16 + 256);
    if (need <= ws_size) break;
    CAP1 >>= 1;
  }
  size_t o_l1  = take((size_t)CAP1 * 4);
  size_t o_h0  = take((size_t)CAP1 * 128 * 4);
  size_t o_hh1 = take((size_t)CAP1 * 512 * 4);
  size_t o_es1 = take((size_t)CAP1 * 16);
  size_t o_ed1 = take((size_t)CAP1 * 16);

  int* cnts  = (int*)(B + o_cnt);   // [0]=cnt3 [1]=cnt2 [2]=cnt1 [3]=cE1 [4]=cE2 [5]=cE3 [8]=simsum(float)
  int* m3    = (int*)(B + o_map);
  int* m2    = m3 + N;
  int* m1    = m2 + N;
  int* list3 = (int*)(B + o_l3);
  int* list2 = (int*)(B + o_l2);
  int* list1 = (int*)(B + o_l1);
  float* tp  = (float*)(B + o_tp);
  int* e1s = (int*)(B + o_e1s); int* e1d = (int*)(B + o_e1d);
  int* e2s = (int*)(B + o_e2s); int* e2d = (int*)(B + o_e2d);
  int* e3s = (int*)(B + o_e3s); int* e3d = (int*)(B + o_e3d);
  float* h0  = (float*)(B + o_h0);
  float* hh1 = (float*)(B + o_hh1);
  float* es1 = (float*)(B + o_es1); float* ed1 = (float*)(B + o_ed1);
  float* h1  = (float*)(B + o_h1);
  float* hh2 = (float*)(B + o_hh2);
  float* es2 = (float*)(B + o_es2); float* ed2 = (float*)(B + o_ed2);
  float* h2  = (float*)(B + o_h2);
  float* hh3 = (float*)(B + o_hh3);
  float* es3 = (float*)(B + o_es3); float* ed3 = (float*)(B + o_ed3);
  float* h3  = (float*)(B + o_h3);
  float* simsum = (float*)&cnts[8];

  k_init_pack<<<1024, 256, 0, stream>>>(x, tp, m3, cnts, N);
  k_sim_mark3<<<1024, 256, 0, stream>>>(tp, src0, dst0, E, simsum, m3, list3, &cnts[0], CAP3);
  k_mark_claim<<<1024, 256, 0, stream>>>(src0, dst0, E, m3, list3, &cnts[0], CAP3,
                                         m2, list2, &cnts[1], CAP2);
  k_mark_claim<<<1024, 256, 0, stream>>>(src0, dst0, E, m2, list2, &cnts[1], CAP2,
                                         m1, list1, &cnts[2], CAP1);
  k_extract<<<1024, 256, 0, stream>>>(src0, dst0, E, m1, m2, m3,
                                      e1s, e1d, &cnts[3], e2s, e2d, &cnts[4], e3s, e3d, &cnts[5],
                                      CAPE1, CAPE2, CAPE3);
  k_h0proj1<<<2048, 256, 0, stream>>>(x, W_in, b_in, g1W, g1as, g1ad,
                                      list1, &cnts[2], CAP1, h0, hh1, es1, ed1);
  k_gat<128, 512, true, false><<<256, 512, 0, stream>>>(
      list2, &cnts[1], CAP2, m1, e1s, e1d, &cnts[3], CAPE1,
      hh1, es1, ed1, h0, g1b, r1W, r1b, n1g, n1b, simsum, tw, E, h1,
      g2W, g2as, g2ad, hh2, es2, ed2,
      nullptr, nullptr, nullptr, nullptr, nullptr, nullptr, nullptr);
  k_gat<128, 256, true, false><<<64, 512, 0, stream>>>(
      list3, &cnts[0], CAP3, m2, e2s, e2d, &cnts[4], CAPE2,
      hh2, es2, ed2, h1, g2b, r2W, r2b, n2g, n2b, simsum, tw, E, h2,
      g3W, g3as, g3ad, hh3, es3, ed3,
      nullptr, nullptr, nullptr, nullptr, nullptr, nullptr, nullptr);
  k_gat<64, 0, false, true><<<1, 256, 0, stream>>>(
      list3, &cnts[0], CAP3, m3, e3s, e3d, &cnts[5], CAPE3,
      hh3, es3, ed3, h2, g3b, r3W, r3b, n3g, n3b, simsum, tw, E, h3,
      nullptr, nullptr, nullptr, nullptr, nullptr, nullptr,
      c1W, c1b, clg, clb, c2W, c2b, dout);
}